// Round 2
// baseline (300.085 us; speedup 1.0000x reference)
//
#include <hip/hip_runtime.h>

#define Bn 32
#define Cc 128
#define Nn 307
#define Ll 12
#define LH 13
#define LAYERS 4
#define BN_EPS 1e-5f
#define SCW (Cc + 1)  // padded LDS stride

// ============================================================================
// G1[ch][l][b][t0][n] = sum_c X[b,c,n,t] * c1[l,c]
// grid (10 ntiles, 32 b, 2 ch), block 256 = 8 c-chunks(16c) x 32 n
// Zeroes the unused t-plane for BOTH channels so all LH rows are valid.
// ============================================================================
__global__ __launch_bounds__(256) void k_g1(const float* __restrict__ XL,
                                            const float* __restrict__ XH,
                                            const float* __restrict__ lc1,
                                            const float* __restrict__ hc1,
                                            float* __restrict__ G1) {
    __shared__ float s_c1[LAYERS * Cc];
    __shared__ float sred[48 * 257];  // [j][tid], stride 257 -> conflict-free
    int tile = blockIdx.x;  // 0..9
    int b = blockIdx.y;
    int ch = blockIdx.z;
    const float* X = ch ? XH : XL;
    const float* c1 = ch ? hc1 : lc1;
    int tid = threadIdx.x;
    for (int j = tid; j < LAYERS * Cc; j += 256) s_c1[j] = c1[j];
    __syncthreads();
    int nl = tid & 31;
    int chunk = tid >> 5;  // 0..7, 16 c each
    int n = tile * 32 + nl;
    float acc[48];
#pragma unroll
    for (int j = 0; j < 48; ++j) acc[j] = 0.f;
    if (n < Nn) {
        const float* px = X + ((size_t)(b * Cc + chunk * 16) * Nn + n) * Ll;
#pragma unroll 2
        for (int i = 0; i < 16; ++i) {
            float4 v0 = *(const float4*)(px);
            float4 v1 = *(const float4*)(px + 4);
            float4 v2 = *(const float4*)(px + 8);
            float xv[12] = {v0.x, v0.y, v0.z, v0.w, v1.x, v1.y,
                            v1.z, v1.w, v2.x, v2.y, v2.z, v2.w};
            int c = chunk * 16 + i;
#pragma unroll
            for (int l = 0; l < LAYERS; ++l) {
                float wv = s_c1[l * Cc + c];
#pragma unroll
                for (int t = 0; t < 12; ++t) acc[l * 12 + t] += xv[t] * wv;
            }
            px += (size_t)Nn * Ll;
        }
    }
#pragma unroll
    for (int j = 0; j < 48; ++j) sred[j * 257 + tid] = acc[j];
    __syncthreads();
    size_t cb = (size_t)ch * LAYERS * Bn * (LH * Nn);
    for (int o = tid; o < 1536; o += 256) {  // 32 nl x 48 j
        int onl = o & 31, j = o >> 5;
        float v = 0.f;
#pragma unroll
        for (int k = 0; k < 8; ++k) v += sred[j * 257 + k * 32 + onl];
        int nn = tile * 32 + onl;
        if (nn < Nn) {
            int l = j / 12, t = j % 12;
            int t0 = ch ? (t + 1) : t;  // high channel shifted by left-pad
            G1[cb + ((size_t)l * Bn + b) * (LH * Nn) + (size_t)t0 * Nn + nn] = v;
        }
    }
    if (tid < 128) {  // zero the unused t-plane (ch0: t0=12, ch1: t0=0)
        int l = tid >> 5, onl = tid & 31;
        int nn = tile * 32 + onl;
        int t0z = ch ? 0 : (LH - 1);
        if (nn < Nn)
            G1[cb + ((size_t)l * Bn + b) * (LH * Nn) + (size_t)t0z * Nn + nn] = 0.f;
    }
}

// ============================================================================
// G2[ch][l][b][t0][c] = sum_n X[b,c,n,t] * c2[l,n]
// grid (32 ctiles, 32 b, 2 ch), block 256 = 4 waves (one c each), lanes span n.
// ============================================================================
__global__ __launch_bounds__(256) void k_g2(const float* __restrict__ XL,
                                            const float* __restrict__ XH,
                                            const float* __restrict__ lc2,
                                            const float* __restrict__ hc2,
                                            float* __restrict__ G2) {
    __shared__ float s_c2[LAYERS * Nn];
    __shared__ float sred[4 * 48 * 65];  // [w][j][lane], stride 65
    int ctile = blockIdx.x;  // 0..31 (4 c each)
    int b = blockIdx.y;
    int ch = blockIdx.z;
    const float* X = ch ? XH : XL;
    const float* c2 = ch ? hc2 : lc2;
    int tid = threadIdx.x;
    for (int j = tid; j < LAYERS * Nn; j += 256) s_c2[j] = c2[j];
    __syncthreads();
    int w = tid >> 6, lane = tid & 63;
    int c = ctile * 4 + w;
    float acc[48];
#pragma unroll
    for (int j = 0; j < 48; ++j) acc[j] = 0.f;
    const float* pb = X + (size_t)(b * Cc + c) * Nn * Ll;
    for (int k = 0; k < 5; ++k) {
        int n = k * 64 + lane;
        if (n < Nn) {
            const float* px = pb + (size_t)n * Ll;
            float4 v0 = *(const float4*)(px);
            float4 v1 = *(const float4*)(px + 4);
            float4 v2 = *(const float4*)(px + 8);
            float xv[12] = {v0.x, v0.y, v0.z, v0.w, v1.x, v1.y,
                            v1.z, v1.w, v2.x, v2.y, v2.z, v2.w};
#pragma unroll
            for (int l = 0; l < LAYERS; ++l) {
                float wv = s_c2[l * Nn + n];
#pragma unroll
                for (int t = 0; t < 12; ++t) acc[l * 12 + t] += xv[t] * wv;
            }
        }
    }
#pragma unroll
    for (int j = 0; j < 48; ++j) sred[(w * 48 + j) * 65 + lane] = acc[j];
    __syncthreads();
    size_t cb = (size_t)ch * LAYERS * Bn * (LH * Cc);
    if (tid < 192) {  // 4 w x 48 j outputs
        int ww = tid / 48, j = tid % 48;
        float v = 0.f;
        for (int k2 = 0; k2 < 64; ++k2) v += sred[(ww * 48 + j) * 65 + k2];
        int l = j / 12, t = j % 12;
        int t0 = ch ? (t + 1) : t;
        int cc2 = ctile * 4 + ww;
        G2[cb + ((size_t)l * Bn + b) * (LH * Cc) + (size_t)t0 * Cc + cc2] = v;
    } else if (ch && tid < 208) {  // zero plane t0=0 for high channel
        int r = tid - 192;
        int l = r >> 2, ww = r & 3;
        G2[cb + ((size_t)l * Bn + b) * (LH * Cc) + ctile * 4 + ww] = 0.f;
    }
}

// ============================================================================
// GW[ch][l][row=(b*LH+t0)][c] = sum_n G1[ch][l][row][n] * w[ch][l][n][c]
// Batched GEMM: 416 rows x 128 c x K=307 per (ch,l).
// grid (104 row-tiles of 4, 8 chl) = 832 blocks; block 256 = 2 n-halves x 128 c.
// G1 rows staged in LDS (broadcast reads); w streamed (L2-resident, 1.26 MB).
// ============================================================================
#define GWR 4
__global__ __launch_bounds__(256) void k_gw(const float* __restrict__ lw,
                                            const float* __restrict__ hw,
                                            const float* __restrict__ G1,
                                            float* __restrict__ GW) {
    __shared__ float sG1[GWR * Nn];
    __shared__ float sred[2][GWR][Cc];
    int tile = blockIdx.x;  // 0..103
    int chl = blockIdx.y;   // ch*4 + l
    int ch = chl >> 2, l = chl & 3;
    const float* w = (ch ? hw : lw) + (size_t)l * Nn * Cc;
    const float* g1 = G1 + (size_t)chl * Bn * (LH * Nn) + (size_t)tile * GWR * Nn;
    int tid = threadIdx.x;
    for (int i = tid; i < GWR * Nn; i += 256) sG1[i] = g1[i];
    __syncthreads();
    int half = tid >> 7, c = tid & 127;
    float a0 = 0.f, a1 = 0.f, a2 = 0.f, a3 = 0.f;
    int n0 = half ? 154 : 0;
    int n1 = half ? Nn : 154;
    for (int n = n0; n < n1; ++n) {
        float wv = w[(size_t)n * Cc + c];
        a0 += sG1[0 * Nn + n] * wv;
        a1 += sG1[1 * Nn + n] * wv;
        a2 += sG1[2 * Nn + n] * wv;
        a3 += sG1[3 * Nn + n] * wv;
    }
    sred[half][0][c] = a0;
    sred[half][1][c] = a1;
    sred[half][2][c] = a2;
    sred[half][3][c] = a3;
    __syncthreads();
    float* out = GW + (size_t)chl * Bn * (LH * Cc) + (size_t)tile * GWR * Cc;
    for (int o = tid; o < GWR * Cc; o += 256) {
        int j = o >> 7, cc = o & 127;
        out[o] = sred[0][j][cc] + sred[1][j][cc];
    }
}

// ============================================================================
// M[ch,l,b][t0][t1] = sum_c GW[ch,l,b,t0,c] * G2[ch,l,b,t1,c]
// 256 blocks (one per ch,l,b), LDS-staged, tiny.
// ============================================================================
__global__ __launch_bounds__(256) void k_m(const float* __restrict__ GW,
                                           const float* __restrict__ G2,
                                           float* __restrict__ M) {
    __shared__ float sGW[LH][SCW];
    __shared__ float sG2[LH][SCW];
    int blk = blockIdx.x;  // (ch*LAYERS + l)*Bn + b
    int ch = blk >> 7;
    int T = ch ? LH : Ll;
    const float* gw = GW + (size_t)blk * (LH * Cc);
    const float* g2 = G2 + (size_t)blk * (LH * Cc);
    int tid = threadIdx.x;
    for (int i = tid; i < LH * Cc; i += 256) {
        int t = i >> 7, c = i & 127;
        sGW[t][c] = gw[i];
        sG2[t][c] = g2[i];
    }
    __syncthreads();
    float* Mo = M + (size_t)blk * (LH * LH);
    for (int i = tid; i < T * T; i += 256) {
        int t0 = i / T, t1 = i % T;
        float a = 0.f;
#pragma unroll 8
        for (int cc = 0; cc < Cc; ++cc) a += sGW[t0][cc] * sG2[t1][cc];
        Mo[t0 * LH + t1] = a;
    }
}

// ============================================================================
// Chain: 5 grid-wide launches (64 blocks = one per (ch,b)); kernel boundaries
// provide the cross-b sync BatchNorm needs. (unchanged, verified)
// ============================================================================
template <int T>
__device__ __forceinline__ void first_impl(int ch, int b,
                                           const float* __restrict__ M,
                                           const float* __restrict__ bb,
                                           const float* __restrict__ v,
                                           float* __restrict__ Lg,
                                           float* __restrict__ Stats) {
    const int TT = T * T;
    __shared__ float sS[LH * LH];
    __shared__ float sA[LH * LH];
    int tid = threadIdx.x;
    const float* Ml = M + ((size_t)(ch * LAYERS + 0) * Bn + b) * (LH * LH);
    if (tid < TT) {
        int t = tid / T, q = tid % T;
        float a = bb[tid] + Ml[t * LH + q];
        sS[tid] = 1.f / (1.f + expf(-a));
    }
    __syncthreads();
    if (tid < TT) {
        int t = tid / T, q = tid % T;
        float a = 0.f;
#pragma unroll
        for (int k = 0; k < T; ++k) a += v[t * T + k] * sS[k * T + q];
        sA[tid] = a;
        Lg[(size_t)(ch * Bn + b) * (LH * LH) + tid] = a;
    }
    __syncthreads();
    if (tid < T) {
        float s = 0.f, ss = 0.f;
#pragma unroll
        for (int t = 0; t < T; ++t) {
            float x = sA[t * T + tid];
            s += x;
            ss += x * x;
        }
        float* St = Stats + (size_t)(0 * 2 + ch) * 2 * (LH * Bn);
        St[tid * Bn + b] = s;
        St[LH * Bn + tid * Bn + b] = ss;
    }
}

__global__ __launch_bounds__(192) void k_first(const float* __restrict__ M,
                                               const float* __restrict__ lb,
                                               const float* __restrict__ lv,
                                               const float* __restrict__ hb,
                                               const float* __restrict__ hv,
                                               float* __restrict__ Lg,
                                               float* __restrict__ Stats) {
    int ch = blockIdx.x >> 5, b = blockIdx.x & 31;
    if (ch == 0)
        first_impl<Ll>(0, b, M, lb, lv, Lg, Stats);
    else
        first_impl<LH>(1, b, M, hb, hv, Lg, Stats);
}

template <int T>
__device__ __forceinline__ void mid_impl(int ch, int b, int l,
                                         const float* __restrict__ M,
                                         const float* __restrict__ bb_all,
                                         const float* __restrict__ v_all,
                                         const float* __restrict__ g_all,
                                         const float* __restrict__ be_all,
                                         float* __restrict__ Lg,
                                         float* __restrict__ Stats,
                                         float* __restrict__ Pws) {
    const int TT = T * T;
    __shared__ float sP[LH * LH], sC[LH * LH], sA[LH * LH], sB[LH * LH], sM[LH * LH];
    __shared__ float sMean[LH], sScale[LH], sShift[LH];
    int tid = threadIdx.x;
    bool first = (l == 0);
    float* Lgb = Lg + (size_t)(ch * Bn + b) * (LH * LH);
    float* Pb = Pws + (size_t)(ch * Bn + b) * (LH * LH);
    if (tid < T) {
        const float* St = Stats + (size_t)(l * 2 + ch) * 2 * (LH * Bn);
        float s = 0.f, ss = 0.f;
        for (int b2 = 0; b2 < Bn; ++b2) {
            s += St[tid * Bn + b2];
            ss += St[LH * Bn + tid * Bn + b2];
        }
        float inv = 1.f / (float)(Bn * T);
        float m = s * inv;
        float var = ss * inv - m * m;
        sMean[tid] = m;
        sScale[tid] = rsqrtf(var + BN_EPS) * g_all[l * T + tid];
        sShift[tid] = be_all[l * T + tid];
    }
    if (tid < TT) {
        sA[tid] = Lgb[tid];
        if (!first) sP[tid] = Pb[tid];
    }
    __syncthreads();
    if (tid < T) {
        float vals[T];
        float mx = -1e30f;
#pragma unroll
        for (int q = 0; q < T; ++q) {
            float x = (sA[tid * T + q] - sMean[q]) * sScale[q] + sShift[q];
            vals[q] = x;
            mx = fmaxf(mx, x);
        }
        float sm = 0.f;
#pragma unroll
        for (int q = 0; q < T; ++q) {
            vals[q] = expf(vals[q] - mx);
            sm += vals[q];
        }
        float inv = 1.f / sm;
#pragma unroll
        for (int q = 0; q < T; ++q) sC[tid * T + q] = vals[q] * inv;
    }
    __syncthreads();
    if (tid < TT) {
        int t0 = tid / T, q = tid % T;
        float a;
        if (first) {
            a = sC[q * T + t0];
        } else {
            a = 0.f;
#pragma unroll
            for (int t = 0; t < T; ++t) a += sP[t0 * T + t] * sC[q * T + t];
        }
        sB[tid] = a;
        Pb[tid] = a;
    }
    const float* Mn = M + ((size_t)(ch * LAYERS + l + 1) * Bn + b) * (LH * LH);
    for (int i = tid; i < T * LH; i += 192) sM[i] = Mn[i];
    __syncthreads();
    if (tid < TT) {
        int t = tid / T, t1 = tid % T;
        float a = 0.f;
#pragma unroll
        for (int t0 = 0; t0 < T; ++t0) a += sB[t0 * T + t] * sM[t0 * LH + t1];
        sA[tid] = a;
    }
    __syncthreads();
    const float* bbn = bb_all + (size_t)(l + 1) * TT;
    if (tid < TT) {
        int t = tid / T, q = tid % T;
        float a = bbn[tid];
#pragma unroll
        for (int t1 = 0; t1 < T; ++t1) a += sA[t * T + t1] * sB[t1 * T + q];
        sP[tid] = 1.f / (1.f + expf(-a));
    }
    __syncthreads();
    const float* vn = v_all + (size_t)(l + 1) * TT;
    if (tid < TT) {
        int t = tid / T, q = tid % T;
        float a = 0.f;
#pragma unroll
        for (int k = 0; k < T; ++k) a += vn[t * T + k] * sP[k * T + q];
        sA[tid] = a;
        Lgb[tid] = a;
    }
    __syncthreads();
    if (tid < T) {
        float s = 0.f, ss = 0.f;
#pragma unroll
        for (int t = 0; t < T; ++t) {
            float x = sA[t * T + tid];
            s += x;
            ss += x * x;
        }
        float* St = Stats + (size_t)((l + 1) * 2 + ch) * 2 * (LH * Bn);
        St[tid * Bn + b] = s;
        St[LH * Bn + tid * Bn + b] = ss;
    }
}

__global__ __launch_bounds__(192) void k_mid(const float* __restrict__ M,
                                             const float* __restrict__ lb,
                                             const float* __restrict__ lv,
                                             const float* __restrict__ lgam,
                                             const float* __restrict__ lbet,
                                             const float* __restrict__ hb,
                                             const float* __restrict__ hv,
                                             const float* __restrict__ hgam,
                                             const float* __restrict__ hbet,
                                             float* __restrict__ Lg,
                                             float* __restrict__ Stats,
                                             float* __restrict__ Pws, int l) {
    int ch = blockIdx.x >> 5, b = blockIdx.x & 31;
    if (ch == 0)
        mid_impl<Ll>(0, b, l, M, lb, lv, lgam, lbet, Lg, Stats, Pws);
    else
        mid_impl<LH>(1, b, l, M, hb, hv, hgam, hbet, Lg, Stats, Pws);
}

template <int T>
__device__ __forceinline__ void last_impl(int ch, int b,
                                          const float* __restrict__ g_all,
                                          const float* __restrict__ be_all,
                                          const float* __restrict__ Lg,
                                          const float* __restrict__ Stats,
                                          const float* __restrict__ Pws,
                                          float* __restrict__ Pcol) {
    const int TT = T * T;
    const int l = LAYERS - 1;
    __shared__ float sP[LH * LH], sC[LH * LH], sA[LH * LH], sB[LH * LH];
    __shared__ float sMean[LH], sScale[LH], sShift[LH];
    int tid = threadIdx.x;
    const float* Lgb = Lg + (size_t)(ch * Bn + b) * (LH * LH);
    const float* Pb = Pws + (size_t)(ch * Bn + b) * (LH * LH);
    if (tid < T) {
        const float* St = Stats + (size_t)(l * 2 + ch) * 2 * (LH * Bn);
        float s = 0.f, ss = 0.f;
        for (int b2 = 0; b2 < Bn; ++b2) {
            s += St[tid * Bn + b2];
            ss += St[LH * Bn + tid * Bn + b2];
        }
        float inv = 1.f / (float)(Bn * T);
        float m = s * inv;
        float var = ss * inv - m * m;
        sMean[tid] = m;
        sScale[tid] = rsqrtf(var + BN_EPS) * g_all[l * T + tid];
        sShift[tid] = be_all[l * T + tid];
    }
    if (tid < TT) {
        sA[tid] = Lgb[tid];
        sP[tid] = Pb[tid];
    }
    __syncthreads();
    if (tid < T) {
        float vals[T];
        float mx = -1e30f;
#pragma unroll
        for (int q = 0; q < T; ++q) {
            float x = (sA[tid * T + q] - sMean[q]) * sScale[q] + sShift[q];
            vals[q] = x;
            mx = fmaxf(mx, x);
        }
        float sm = 0.f;
#pragma unroll
        for (int q = 0; q < T; ++q) {
            vals[q] = expf(vals[q] - mx);
            sm += vals[q];
        }
        float inv = 1.f / sm;
#pragma unroll
        for (int q = 0; q < T; ++q) sC[tid * T + q] = vals[q] * inv;
    }
    __syncthreads();
    if (tid < TT) {
        int t0 = tid / T, q = tid % T;
        float a = 0.f;
#pragma unroll
        for (int t = 0; t < T; ++t) a += sP[t0 * T + t] * sC[q * T + t];
        sB[tid] = a;
    }
    __syncthreads();
    if (tid < T) Pcol[(size_t)ch * Bn * LH + b * LH + tid] = sB[tid * T + (T - 1)];
}

__global__ __launch_bounds__(192) void k_last(const float* __restrict__ lgam,
                                              const float* __restrict__ lbet,
                                              const float* __restrict__ hgam,
                                              const float* __restrict__ hbet,
                                              const float* __restrict__ Lg,
                                              const float* __restrict__ Stats,
                                              const float* __restrict__ Pws,
                                              float* __restrict__ Pcol) {
    int ch = blockIdx.x >> 5, b = blockIdx.x & 31;
    if (ch == 0)
        last_impl<Ll>(0, b, lgam, lbet, Lg, Stats, Pws, Pcol);
    else
        last_impl<LH>(1, b, hgam, hbet, Lg, Stats, Pws, Pcol);
}

// ---- final: residuals + alpha blend using last-column weights (unchanged) ----
__global__ __launch_bounds__(256) void k_final(const float* __restrict__ XL,
                                               const float* __restrict__ XH,
                                               const float* __restrict__ Pcol,
                                               const float* __restrict__ alpha,
                                               float* __restrict__ out) {
    __shared__ float s_pl[Ll];
    __shared__ float s_ph[LH];
    int b = blockIdx.y;
    int tid = threadIdx.x;
    if (tid < Ll) s_pl[tid] = Pcol[b * LH + tid];
    if (tid < LH) s_ph[tid] = Pcol[Bn * LH + b * LH + tid];
    __syncthreads();
    int cn = blockIdx.x * blockDim.x + tid;
    if (cn >= Cc * Nn) return;
    size_t idx = (size_t)b * Cc * Nn + cn;
    const float* pl = XL + idx * Ll;
    const float* ph = XH + idx * Ll;
    float accL = 0.f, accH = 0.f;
#pragma unroll
    for (int t = 0; t < Ll; ++t) {
        accL += pl[t] * s_pl[t];
        accH += ph[t] * s_ph[t + 1];  // high-channel t0=0 plane is the zero pad
    }
    float a = 1.f / (1.f + expf(-alpha[0]));
    float xl = pl[Ll - 1] + accL;
    float xh = ph[Ll - 1] + accH;
    out[idx] = a * xl + (1.f - a) * xh;
}

extern "C" void kernel_launch(void* const* d_in, const int* in_sizes, int n_in,
                              void* d_out, int out_size, void* d_ws, size_t ws_size,
                              hipStream_t stream) {
    const float* XL = (const float*)d_in[0];
    const float* XH = (const float*)d_in[1];
    const float* lc1 = (const float*)d_in[2];
    const float* lc2 = (const float*)d_in[3];
    const float* lw = (const float*)d_in[4];
    const float* lb = (const float*)d_in[5];
    const float* lv = (const float*)d_in[6];
    const float* lg = (const float*)d_in[7];
    const float* lbeta = (const float*)d_in[8];
    const float* hc1 = (const float*)d_in[9];
    const float* hc2 = (const float*)d_in[10];
    const float* hw = (const float*)d_in[11];
    const float* hb = (const float*)d_in[12];
    const float* hv = (const float*)d_in[13];
    const float* hg = (const float*)d_in[14];
    const float* hbeta = (const float*)d_in[15];
    const float* alpha = (const float*)d_in[16];
    float* out = (float*)d_out;

    float* ws = (float*)d_ws;
    float* G1 = ws;                                          // 2*4*32*13*307
    float* G2 = G1 + (size_t)2 * LAYERS * Bn * LH * Nn;      // 2*4*32*13*128
    float* M = G2 + (size_t)2 * LAYERS * Bn * LH * Cc;       // 2*4*32*13*13
    float* Pcol = M + (size_t)2 * LAYERS * Bn * LH * LH;     // 2*32*13
    float* Stats = Pcol + (size_t)2 * Bn * LH;               // 16*13*32
    float* Lg = Stats + (size_t)4 * LAYERS * LH * Bn;        // 2*32*169
    float* Pws = Lg + (size_t)2 * Bn * LH * LH;              // 2*32*169
    float* GW = Pws + (size_t)2 * Bn * LH * LH;              // 2*4*32*13*128

    k_g1<<<dim3(10, 32, 2), 256, 0, stream>>>(XL, XH, lc1, hc1, G1);
    k_g2<<<dim3(32, 32, 2), 256, 0, stream>>>(XL, XH, lc2, hc2, G2);
    k_gw<<<dim3(104, 8), 256, 0, stream>>>(lw, hw, G1, GW);
    k_m<<<256, 256, 0, stream>>>(GW, G2, M);
    k_first<<<64, 192, 0, stream>>>(M, lb, lv, hb, hv, Lg, Stats);
    k_mid<<<64, 192, 0, stream>>>(M, lb, lv, lg, lbeta, hb, hv, hg, hbeta, Lg, Stats, Pws, 0);
    k_mid<<<64, 192, 0, stream>>>(M, lb, lv, lg, lbeta, hb, hv, hg, hbeta, Lg, Stats, Pws, 1);
    k_mid<<<64, 192, 0, stream>>>(M, lb, lv, lg, lbeta, hb, hv, hg, hbeta, Lg, Stats, Pws, 2);
    k_last<<<64, 192, 0, stream>>>(lg, lbeta, hg, hbeta, Lg, Stats, Pws, Pcol);
    k_final<<<dim3((Cc * Nn + 255) / 256, Bn), 256, 0, stream>>>(XL, XH, Pcol, alpha, out);
}

// Round 3
// 254.516 us; speedup vs baseline: 1.1790x; 1.1790x over previous
//
#include <hip/hip_runtime.h>

#define Bn 32
#define Cc 128
#define Nn 307
#define Ll 12
#define LH 13
#define LAYERS 4
#define BN_EPS 1e-5f
#define SCW (Cc + 1)  // padded LDS stride

// ============================================================================
// G1[ch][l][b][t0][n] = sum_c X[b,c,n,t] * c1[l,c]
// grid (10 ntiles, 32 b, 2 ch), block 256 = 8 c-chunks(16c) x 32 n
// Zeroes the unused t-plane for BOTH channels so all LH rows are valid.
// ============================================================================
__global__ __launch_bounds__(256) void k_g1(const float* __restrict__ XL,
                                            const float* __restrict__ XH,
                                            const float* __restrict__ lc1,
                                            const float* __restrict__ hc1,
                                            float* __restrict__ G1) {
    __shared__ float s_c1[LAYERS * Cc];
    __shared__ float sred[48 * 257];  // [j][tid], stride 257 -> conflict-free
    int tile = blockIdx.x;  // 0..9
    int b = blockIdx.y;
    int ch = blockIdx.z;
    const float* X = ch ? XH : XL;
    const float* c1 = ch ? hc1 : lc1;
    int tid = threadIdx.x;
    for (int j = tid; j < LAYERS * Cc; j += 256) s_c1[j] = c1[j];
    __syncthreads();
    int nl = tid & 31;
    int chunk = tid >> 5;  // 0..7, 16 c each
    int n = tile * 32 + nl;
    float acc[48];
#pragma unroll
    for (int j = 0; j < 48; ++j) acc[j] = 0.f;
    if (n < Nn) {
        const float* px = X + ((size_t)(b * Cc + chunk * 16) * Nn + n) * Ll;
#pragma unroll 2
        for (int i = 0; i < 16; ++i) {
            float4 v0 = *(const float4*)(px);
            float4 v1 = *(const float4*)(px + 4);
            float4 v2 = *(const float4*)(px + 8);
            float xv[12] = {v0.x, v0.y, v0.z, v0.w, v1.x, v1.y,
                            v1.z, v1.w, v2.x, v2.y, v2.z, v2.w};
            int c = chunk * 16 + i;
#pragma unroll
            for (int l = 0; l < LAYERS; ++l) {
                float wv = s_c1[l * Cc + c];
#pragma unroll
                for (int t = 0; t < 12; ++t) acc[l * 12 + t] += xv[t] * wv;
            }
            px += (size_t)Nn * Ll;
        }
    }
#pragma unroll
    for (int j = 0; j < 48; ++j) sred[j * 257 + tid] = acc[j];
    __syncthreads();
    size_t cb = (size_t)ch * LAYERS * Bn * (LH * Nn);
    for (int o = tid; o < 1536; o += 256) {  // 32 nl x 48 j
        int onl = o & 31, j = o >> 5;
        float v = 0.f;
#pragma unroll
        for (int k = 0; k < 8; ++k) v += sred[j * 257 + k * 32 + onl];
        int nn = tile * 32 + onl;
        if (nn < Nn) {
            int l = j / 12, t = j % 12;
            int t0 = ch ? (t + 1) : t;  // high channel shifted by left-pad
            G1[cb + ((size_t)l * Bn + b) * (LH * Nn) + (size_t)t0 * Nn + nn] = v;
        }
    }
    if (tid < 128) {  // zero the unused t-plane (ch0: t0=12, ch1: t0=0)
        int l = tid >> 5, onl = tid & 31;
        int nn = tile * 32 + onl;
        int t0z = ch ? 0 : (LH - 1);
        if (nn < Nn)
            G1[cb + ((size_t)l * Bn + b) * (LH * Nn) + (size_t)t0z * Nn + nn] = 0.f;
    }
}

// ============================================================================
// G2[ch][l][b][t0][c] = sum_n X[b,c,n,t] * c2[l,n]
// grid (32 ctiles, 32 b, 2 ch), block 256 = 4 waves (one c each), lanes span n.
// ============================================================================
__global__ __launch_bounds__(256) void k_g2(const float* __restrict__ XL,
                                            const float* __restrict__ XH,
                                            const float* __restrict__ lc2,
                                            const float* __restrict__ hc2,
                                            float* __restrict__ G2) {
    __shared__ float s_c2[LAYERS * Nn];
    __shared__ float sred[4 * 48 * 65];  // [w][j][lane], stride 65
    int ctile = blockIdx.x;  // 0..31 (4 c each)
    int b = blockIdx.y;
    int ch = blockIdx.z;
    const float* X = ch ? XH : XL;
    const float* c2 = ch ? hc2 : lc2;
    int tid = threadIdx.x;
    for (int j = tid; j < LAYERS * Nn; j += 256) s_c2[j] = c2[j];
    __syncthreads();
    int w = tid >> 6, lane = tid & 63;
    int c = ctile * 4 + w;
    float acc[48];
#pragma unroll
    for (int j = 0; j < 48; ++j) acc[j] = 0.f;
    const float* pb = X + (size_t)(b * Cc + c) * Nn * Ll;
    for (int k = 0; k < 5; ++k) {
        int n = k * 64 + lane;
        if (n < Nn) {
            const float* px = pb + (size_t)n * Ll;
            float4 v0 = *(const float4*)(px);
            float4 v1 = *(const float4*)(px + 4);
            float4 v2 = *(const float4*)(px + 8);
            float xv[12] = {v0.x, v0.y, v0.z, v0.w, v1.x, v1.y,
                            v1.z, v1.w, v2.x, v2.y, v2.z, v2.w};
#pragma unroll
            for (int l = 0; l < LAYERS; ++l) {
                float wv = s_c2[l * Nn + n];
#pragma unroll
                for (int t = 0; t < 12; ++t) acc[l * 12 + t] += xv[t] * wv;
            }
        }
    }
#pragma unroll
    for (int j = 0; j < 48; ++j) sred[(w * 48 + j) * 65 + lane] = acc[j];
    __syncthreads();
    size_t cb = (size_t)ch * LAYERS * Bn * (LH * Cc);
    if (tid < 192) {  // 4 w x 48 j outputs
        int ww = tid / 48, j = tid % 48;
        float v = 0.f;
        for (int k2 = 0; k2 < 64; ++k2) v += sred[(ww * 48 + j) * 65 + k2];
        int l = j / 12, t = j % 12;
        int t0 = ch ? (t + 1) : t;
        int cc2 = ctile * 4 + ww;
        G2[cb + ((size_t)l * Bn + b) * (LH * Cc) + (size_t)t0 * Cc + cc2] = v;
    } else if (ch && tid < 208) {  // zero plane t0=0 for high channel
        int r = tid - 192;
        int l = r >> 2, ww = r & 3;
        G2[cb + ((size_t)l * Bn + b) * (LH * Cc) + ctile * 4 + ww] = 0.f;
    }
}

// ============================================================================
// GW[ch][l][row=(b*LH+t0)][c] = sum_n G1[ch][l][row][n] * w[ch][l][n][c]
// grid (104 row-tiles of 4, 8 chl); block 256 = 32 c-quads x 8 n-stripes.
// float4 w loads, 4-deep manual unroll -> 4 independent dwordx4 in flight.
// ============================================================================
#define GWR 4
__global__ __launch_bounds__(256) void k_gw(const float* __restrict__ lw,
                                            const float* __restrict__ hw,
                                            const float* __restrict__ G1,
                                            float* __restrict__ GW) {
    __shared__ float sG1[GWR * Nn];
    __shared__ float sred[8][GWR][Cc];  // 16 KB
    int tile = blockIdx.x;  // 0..103
    int chl = blockIdx.y;   // ch*4 + l
    int ch = chl >> 2, l = chl & 3;
    const float* w = (ch ? hw : lw) + (size_t)l * Nn * Cc;
    const float* g1 = G1 + (size_t)chl * Bn * (LH * Nn) + (size_t)tile * GWR * Nn;
    int tid = threadIdx.x;
    // stage G1 tile (4 contiguous rows = 1228 floats, 16B-aligned)
    for (int i = tid; i < GWR * Nn / 4; i += 256)
        ((float4*)sG1)[i] = ((const float4*)g1)[i];
    __syncthreads();
    int c4 = (tid & 31) * 4;  // c base (0,4,...,124)
    int stripe = tid >> 5;    // 0..7, n = stripe, stripe+8, ...
    float4 a0 = {0.f, 0.f, 0.f, 0.f}, a1 = a0, a2 = a0, a3 = a0;
#define GW_FMA(wv, nn)                                         \
    {                                                          \
        float g0 = sG1[0 * Nn + (nn)];                         \
        float g1v = sG1[1 * Nn + (nn)];                        \
        float g2v = sG1[2 * Nn + (nn)];                        \
        float g3v = sG1[3 * Nn + (nn)];                        \
        a0.x += wv.x * g0;  a0.y += wv.y * g0;                 \
        a0.z += wv.z * g0;  a0.w += wv.w * g0;                 \
        a1.x += wv.x * g1v; a1.y += wv.y * g1v;                \
        a1.z += wv.z * g1v; a1.w += wv.w * g1v;                \
        a2.x += wv.x * g2v; a2.y += wv.y * g2v;                \
        a2.z += wv.z * g2v; a2.w += wv.w * g2v;                \
        a3.x += wv.x * g3v; a3.y += wv.y * g3v;                \
        a3.z += wv.z * g3v; a3.w += wv.w * g3v;                \
    }
    int n = stripe;
    for (; n + 24 < Nn; n += 32) {  // 4 strided loads in flight
        float4 w0 = *(const float4*)(w + (size_t)n * Cc + c4);
        float4 w1 = *(const float4*)(w + (size_t)(n + 8) * Cc + c4);
        float4 w2 = *(const float4*)(w + (size_t)(n + 16) * Cc + c4);
        float4 w3 = *(const float4*)(w + (size_t)(n + 24) * Cc + c4);
        GW_FMA(w0, n);
        GW_FMA(w1, n + 8);
        GW_FMA(w2, n + 16);
        GW_FMA(w3, n + 24);
    }
    for (; n < Nn; n += 8) {
        float4 w0 = *(const float4*)(w + (size_t)n * Cc + c4);
        GW_FMA(w0, n);
    }
#undef GW_FMA
    *(float4*)&sred[stripe][0][c4] = a0;
    *(float4*)&sred[stripe][1][c4] = a1;
    *(float4*)&sred[stripe][2][c4] = a2;
    *(float4*)&sred[stripe][3][c4] = a3;
    __syncthreads();
    float* out = GW + (size_t)chl * Bn * (LH * Cc) + (size_t)tile * GWR * Cc;
    for (int o = tid; o < GWR * Cc; o += 256) {
        int r = o >> 7, cc = o & 127;
        float v = 0.f;
#pragma unroll
        for (int s = 0; s < 8; ++s) v += sred[s][r][cc];
        out[o] = v;
    }
}

// ============================================================================
// M[ch,l,b][t0][t1] = sum_c GW[ch,l,b,t0,c] * G2[ch,l,b,t1,c]
// 256 blocks (one per ch,l,b), LDS-staged, tiny.
// ============================================================================
__global__ __launch_bounds__(256) void k_m(const float* __restrict__ GW,
                                           const float* __restrict__ G2,
                                           float* __restrict__ M) {
    __shared__ float sGW[LH][SCW];
    __shared__ float sG2[LH][SCW];
    int blk = blockIdx.x;  // (ch*LAYERS + l)*Bn + b
    int ch = blk >> 7;
    int T = ch ? LH : Ll;
    const float* gw = GW + (size_t)blk * (LH * Cc);
    const float* g2 = G2 + (size_t)blk * (LH * Cc);
    int tid = threadIdx.x;
    for (int i = tid; i < LH * Cc; i += 256) {
        int t = i >> 7, c = i & 127;
        sGW[t][c] = gw[i];
        sG2[t][c] = g2[i];
    }
    __syncthreads();
    float* Mo = M + (size_t)blk * (LH * LH);
    for (int i = tid; i < T * T; i += 256) {
        int t0 = i / T, t1 = i % T;
        float a = 0.f;
#pragma unroll 8
        for (int cc = 0; cc < Cc; ++cc) a += sGW[t0][cc] * sG2[t1][cc];
        Mo[t0 * LH + t1] = a;
    }
}

// ============================================================================
// Chain: 5 grid-wide launches (64 blocks = one per (ch,b)); kernel boundaries
// provide the cross-b sync BatchNorm needs. (unchanged, verified)
// ============================================================================
template <int T>
__device__ __forceinline__ void first_impl(int ch, int b,
                                           const float* __restrict__ M,
                                           const float* __restrict__ bb,
                                           const float* __restrict__ v,
                                           float* __restrict__ Lg,
                                           float* __restrict__ Stats) {
    const int TT = T * T;
    __shared__ float sS[LH * LH];
    __shared__ float sA[LH * LH];
    int tid = threadIdx.x;
    const float* Ml = M + ((size_t)(ch * LAYERS + 0) * Bn + b) * (LH * LH);
    if (tid < TT) {
        int t = tid / T, q = tid % T;
        float a = bb[tid] + Ml[t * LH + q];
        sS[tid] = 1.f / (1.f + expf(-a));
    }
    __syncthreads();
    if (tid < TT) {
        int t = tid / T, q = tid % T;
        float a = 0.f;
#pragma unroll
        for (int k = 0; k < T; ++k) a += v[t * T + k] * sS[k * T + q];
        sA[tid] = a;
        Lg[(size_t)(ch * Bn + b) * (LH * LH) + tid] = a;
    }
    __syncthreads();
    if (tid < T) {
        float s = 0.f, ss = 0.f;
#pragma unroll
        for (int t = 0; t < T; ++t) {
            float x = sA[t * T + tid];
            s += x;
            ss += x * x;
        }
        float* St = Stats + (size_t)(0 * 2 + ch) * 2 * (LH * Bn);
        St[tid * Bn + b] = s;
        St[LH * Bn + tid * Bn + b] = ss;
    }
}

__global__ __launch_bounds__(192) void k_first(const float* __restrict__ M,
                                               const float* __restrict__ lb,
                                               const float* __restrict__ lv,
                                               const float* __restrict__ hb,
                                               const float* __restrict__ hv,
                                               float* __restrict__ Lg,
                                               float* __restrict__ Stats) {
    int ch = blockIdx.x >> 5, b = blockIdx.x & 31;
    if (ch == 0)
        first_impl<Ll>(0, b, M, lb, lv, Lg, Stats);
    else
        first_impl<LH>(1, b, M, hb, hv, Lg, Stats);
}

template <int T>
__device__ __forceinline__ void mid_impl(int ch, int b, int l,
                                         const float* __restrict__ M,
                                         const float* __restrict__ bb_all,
                                         const float* __restrict__ v_all,
                                         const float* __restrict__ g_all,
                                         const float* __restrict__ be_all,
                                         float* __restrict__ Lg,
                                         float* __restrict__ Stats,
                                         float* __restrict__ Pws) {
    const int TT = T * T;
    __shared__ float sP[LH * LH], sC[LH * LH], sA[LH * LH], sB[LH * LH], sM[LH * LH];
    __shared__ float sMean[LH], sScale[LH], sShift[LH];
    int tid = threadIdx.x;
    bool first = (l == 0);
    float* Lgb = Lg + (size_t)(ch * Bn + b) * (LH * LH);
    float* Pb = Pws + (size_t)(ch * Bn + b) * (LH * LH);
    if (tid < T) {
        const float* St = Stats + (size_t)(l * 2 + ch) * 2 * (LH * Bn);
        float s = 0.f, ss = 0.f;
        for (int b2 = 0; b2 < Bn; ++b2) {
            s += St[tid * Bn + b2];
            ss += St[LH * Bn + tid * Bn + b2];
        }
        float inv = 1.f / (float)(Bn * T);
        float m = s * inv;
        float var = ss * inv - m * m;
        sMean[tid] = m;
        sScale[tid] = rsqrtf(var + BN_EPS) * g_all[l * T + tid];
        sShift[tid] = be_all[l * T + tid];
    }
    if (tid < TT) {
        sA[tid] = Lgb[tid];
        if (!first) sP[tid] = Pb[tid];
    }
    __syncthreads();
    if (tid < T) {
        float vals[T];
        float mx = -1e30f;
#pragma unroll
        for (int q = 0; q < T; ++q) {
            float x = (sA[tid * T + q] - sMean[q]) * sScale[q] + sShift[q];
            vals[q] = x;
            mx = fmaxf(mx, x);
        }
        float sm = 0.f;
#pragma unroll
        for (int q = 0; q < T; ++q) {
            vals[q] = expf(vals[q] - mx);
            sm += vals[q];
        }
        float inv = 1.f / sm;
#pragma unroll
        for (int q = 0; q < T; ++q) sC[tid * T + q] = vals[q] * inv;
    }
    __syncthreads();
    if (tid < TT) {
        int t0 = tid / T, q = tid % T;
        float a;
        if (first) {
            a = sC[q * T + t0];
        } else {
            a = 0.f;
#pragma unroll
            for (int t = 0; t < T; ++t) a += sP[t0 * T + t] * sC[q * T + t];
        }
        sB[tid] = a;
        Pb[tid] = a;
    }
    const float* Mn = M + ((size_t)(ch * LAYERS + l + 1) * Bn + b) * (LH * LH);
    for (int i = tid; i < T * LH; i += 192) sM[i] = Mn[i];
    __syncthreads();
    if (tid < TT) {
        int t = tid / T, t1 = tid % T;
        float a = 0.f;
#pragma unroll
        for (int t0 = 0; t0 < T; ++t0) a += sB[t0 * T + t] * sM[t0 * LH + t1];
        sA[tid] = a;
    }
    __syncthreads();
    const float* bbn = bb_all + (size_t)(l + 1) * TT;
    if (tid < TT) {
        int t = tid / T, q = tid % T;
        float a = bbn[tid];
#pragma unroll
        for (int t1 = 0; t1 < T; ++t1) a += sA[t * T + t1] * sB[t1 * T + q];
        sP[tid] = 1.f / (1.f + expf(-a));
    }
    __syncthreads();
    const float* vn = v_all + (size_t)(l + 1) * TT;
    if (tid < TT) {
        int t = tid / T, q = tid % T;
        float a = 0.f;
#pragma unroll
        for (int k = 0; k < T; ++k) a += vn[t * T + k] * sP[k * T + q];
        sA[tid] = a;
        Lgb[tid] = a;
    }
    __syncthreads();
    if (tid < T) {
        float s = 0.f, ss = 0.f;
#pragma unroll
        for (int t = 0; t < T; ++t) {
            float x = sA[t * T + tid];
            s += x;
            ss += x * x;
        }
        float* St = Stats + (size_t)((l + 1) * 2 + ch) * 2 * (LH * Bn);
        St[tid * Bn + b] = s;
        St[LH * Bn + tid * Bn + b] = ss;
    }
}

__global__ __launch_bounds__(192) void k_mid(const float* __restrict__ M,
                                             const float* __restrict__ lb,
                                             const float* __restrict__ lv,
                                             const float* __restrict__ lgam,
                                             const float* __restrict__ lbet,
                                             const float* __restrict__ hb,
                                             const float* __restrict__ hv,
                                             const float* __restrict__ hgam,
                                             const float* __restrict__ hbet,
                                             float* __restrict__ Lg,
                                             float* __restrict__ Stats,
                                             float* __restrict__ Pws, int l) {
    int ch = blockIdx.x >> 5, b = blockIdx.x & 31;
    if (ch == 0)
        mid_impl<Ll>(0, b, l, M, lb, lv, lgam, lbet, Lg, Stats, Pws);
    else
        mid_impl<LH>(1, b, l, M, hb, hv, hgam, hbet, Lg, Stats, Pws);
}

template <int T>
__device__ __forceinline__ void last_impl(int ch, int b,
                                          const float* __restrict__ g_all,
                                          const float* __restrict__ be_all,
                                          const float* __restrict__ Lg,
                                          const float* __restrict__ Stats,
                                          const float* __restrict__ Pws,
                                          float* __restrict__ Pcol) {
    const int TT = T * T;
    const int l = LAYERS - 1;
    __shared__ float sP[LH * LH], sC[LH * LH], sA[LH * LH], sB[LH * LH];
    __shared__ float sMean[LH], sScale[LH], sShift[LH];
    int tid = threadIdx.x;
    const float* Lgb = Lg + (size_t)(ch * Bn + b) * (LH * LH);
    const float* Pb = Pws + (size_t)(ch * Bn + b) * (LH * LH);
    if (tid < T) {
        const float* St = Stats + (size_t)(l * 2 + ch) * 2 * (LH * Bn);
        float s = 0.f, ss = 0.f;
        for (int b2 = 0; b2 < Bn; ++b2) {
            s += St[tid * Bn + b2];
            ss += St[LH * Bn + tid * Bn + b2];
        }
        float inv = 1.f / (float)(Bn * T);
        float m = s * inv;
        float var = ss * inv - m * m;
        sMean[tid] = m;
        sScale[tid] = rsqrtf(var + BN_EPS) * g_all[l * T + tid];
        sShift[tid] = be_all[l * T + tid];
    }
    if (tid < TT) {
        sA[tid] = Lgb[tid];
        sP[tid] = Pb[tid];
    }
    __syncthreads();
    if (tid < T) {
        float vals[T];
        float mx = -1e30f;
#pragma unroll
        for (int q = 0; q < T; ++q) {
            float x = (sA[tid * T + q] - sMean[q]) * sScale[q] + sShift[q];
            vals[q] = x;
            mx = fmaxf(mx, x);
        }
        float sm = 0.f;
#pragma unroll
        for (int q = 0; q < T; ++q) {
            vals[q] = expf(vals[q] - mx);
            sm += vals[q];
        }
        float inv = 1.f / sm;
#pragma unroll
        for (int q = 0; q < T; ++q) sC[tid * T + q] = vals[q] * inv;
    }
    __syncthreads();
    if (tid < TT) {
        int t0 = tid / T, q = tid % T;
        float a = 0.f;
#pragma unroll
        for (int t = 0; t < T; ++t) a += sP[t0 * T + t] * sC[q * T + t];
        sB[tid] = a;
    }
    __syncthreads();
    if (tid < T) Pcol[(size_t)ch * Bn * LH + b * LH + tid] = sB[tid * T + (T - 1)];
}

__global__ __launch_bounds__(192) void k_last(const float* __restrict__ lgam,
                                              const float* __restrict__ lbet,
                                              const float* __restrict__ hgam,
                                              const float* __restrict__ hbet,
                                              const float* __restrict__ Lg,
                                              const float* __restrict__ Stats,
                                              const float* __restrict__ Pws,
                                              float* __restrict__ Pcol) {
    int ch = blockIdx.x >> 5, b = blockIdx.x & 31;
    if (ch == 0)
        last_impl<Ll>(0, b, lgam, lbet, Lg, Stats, Pws, Pcol);
    else
        last_impl<LH>(1, b, hgam, hbet, Lg, Stats, Pws, Pcol);
}

// ---- final: residuals + alpha blend using last-column weights (unchanged) ----
__global__ __launch_bounds__(256) void k_final(const float* __restrict__ XL,
                                               const float* __restrict__ XH,
                                               const float* __restrict__ Pcol,
                                               const float* __restrict__ alpha,
                                               float* __restrict__ out) {
    __shared__ float s_pl[Ll];
    __shared__ float s_ph[LH];
    int b = blockIdx.y;
    int tid = threadIdx.x;
    if (tid < Ll) s_pl[tid] = Pcol[b * LH + tid];
    if (tid < LH) s_ph[tid] = Pcol[Bn * LH + b * LH + tid];
    __syncthreads();
    int cn = blockIdx.x * blockDim.x + tid;
    if (cn >= Cc * Nn) return;
    size_t idx = (size_t)b * Cc * Nn + cn;
    const float* pl = XL + idx * Ll;
    const float* ph = XH + idx * Ll;
    float accL = 0.f, accH = 0.f;
#pragma unroll
    for (int t = 0; t < Ll; ++t) {
        accL += pl[t] * s_pl[t];
        accH += ph[t] * s_ph[t + 1];  // high-channel t0=0 plane is the zero pad
    }
    float a = 1.f / (1.f + expf(-alpha[0]));
    float xl = pl[Ll - 1] + accL;
    float xh = ph[Ll - 1] + accH;
    out[idx] = a * xl + (1.f - a) * xh;
}

extern "C" void kernel_launch(void* const* d_in, const int* in_sizes, int n_in,
                              void* d_out, int out_size, void* d_ws, size_t ws_size,
                              hipStream_t stream) {
    const float* XL = (const float*)d_in[0];
    const float* XH = (const float*)d_in[1];
    const float* lc1 = (const float*)d_in[2];
    const float* lc2 = (const float*)d_in[3];
    const float* lw = (const float*)d_in[4];
    const float* lb = (const float*)d_in[5];
    const float* lv = (const float*)d_in[6];
    const float* lg = (const float*)d_in[7];
    const float* lbeta = (const float*)d_in[8];
    const float* hc1 = (const float*)d_in[9];
    const float* hc2 = (const float*)d_in[10];
    const float* hw = (const float*)d_in[11];
    const float* hb = (const float*)d_in[12];
    const float* hv = (const float*)d_in[13];
    const float* hg = (const float*)d_in[14];
    const float* hbeta = (const float*)d_in[15];
    const float* alpha = (const float*)d_in[16];
    float* out = (float*)d_out;

    float* ws = (float*)d_ws;
    float* G1 = ws;                                          // 2*4*32*13*307
    float* G2 = G1 + (size_t)2 * LAYERS * Bn * LH * Nn;      // 2*4*32*13*128
    float* M = G2 + (size_t)2 * LAYERS * Bn * LH * Cc;       // 2*4*32*13*13
    float* Pcol = M + (size_t)2 * LAYERS * Bn * LH * LH;     // 2*32*13
    float* Stats = Pcol + (size_t)2 * Bn * LH;               // 16*13*32
    float* Lg = Stats + (size_t)4 * LAYERS * LH * Bn;        // 2*32*169
    float* Pws = Lg + (size_t)2 * Bn * LH * LH;              // 2*32*169
    float* GW = Pws + (size_t)2 * Bn * LH * LH;              // 2*4*32*13*128

    k_g1<<<dim3(10, 32, 2), 256, 0, stream>>>(XL, XH, lc1, hc1, G1);
    k_g2<<<dim3(32, 32, 2), 256, 0, stream>>>(XL, XH, lc2, hc2, G2);
    k_gw<<<dim3(104, 8), 256, 0, stream>>>(lw, hw, G1, GW);
    k_m<<<256, 256, 0, stream>>>(GW, G2, M);
    k_first<<<64, 192, 0, stream>>>(M, lb, lv, hb, hv, Lg, Stats);
    k_mid<<<64, 192, 0, stream>>>(M, lb, lv, lg, lbeta, hb, hv, hg, hbeta, Lg, Stats, Pws, 0);
    k_mid<<<64, 192, 0, stream>>>(M, lb, lv, lg, lbeta, hb, hv, hg, hbeta, Lg, Stats, Pws, 1);
    k_mid<<<64, 192, 0, stream>>>(M, lb, lv, lg, lbeta, hb, hv, hg, hbeta, Lg, Stats, Pws, 2);
    k_last<<<64, 192, 0, stream>>>(lg, lbeta, hg, hbeta, Lg, Stats, Pws, Pcol);
    k_final<<<dim3((Cc * Nn + 255) / 256, Bn), 256, 0, stream>>>(XL, XH, Pcol, alpha, out);
}

// Round 4
// 252.707 us; speedup vs baseline: 1.1875x; 1.0072x over previous
//
#include <hip/hip_runtime.h>

#define Bn 32
#define Cc 128
#define Nn 307
#define Ll 12
#define LH 13
#define LAYERS 4
#define BN_EPS 1e-5f
#define SCW (Cc + 1)   // padded LDS stride
#define G1SZ ((size_t)2 * LAYERS * Bn * LH * Nn)  // one G1 partial buffer

// ============================================================================
// G1p[cs][ch][l][b][t0][n] = sum_{c in half cs} X[b,c,n,t] * c1[l,c]
// grid (20 = cs*10+tile, 32 b, 2 ch), block 256 = 8 chunks(8c) x 32 n.
// shfl pair-reduce (chunk parity) -> sred[48][132] (25 KB) -> 5 blocks/CU.
// k_gw sums the two partial buffers during staging.
// ============================================================================
__global__ __launch_bounds__(256) void k_g1(const float* __restrict__ XL,
                                            const float* __restrict__ XH,
                                            const float* __restrict__ lc1,
                                            const float* __restrict__ hc1,
                                            float* __restrict__ G1) {
    __shared__ float s_c1[LAYERS * Cc];
    __shared__ float sred[48 * 132];
    int bx = blockIdx.x;
    int tile = bx % 10;       // 0..9
    int csplit = bx / 10;     // 0..1
    int b = blockIdx.y;
    int ch = blockIdx.z;
    const float* X = ch ? XH : XL;
    const float* c1 = ch ? hc1 : lc1;
    int tid = threadIdx.x;
    for (int j = tid; j < LAYERS * Cc; j += 256) s_c1[j] = c1[j];
    __syncthreads();
    int nl = tid & 31;
    int chunk = tid >> 5;  // 0..7, 8 c each
    int n = tile * 32 + nl;
    float acc[48];
#pragma unroll
    for (int j = 0; j < 48; ++j) acc[j] = 0.f;
    if (n < Nn) {
        const float* px = X + ((size_t)(b * Cc + csplit * 64 + chunk * 8) * Nn + n) * Ll;
#pragma unroll 4
        for (int i = 0; i < 8; ++i) {
            float4 v0 = *(const float4*)(px);
            float4 v1 = *(const float4*)(px + 4);
            float4 v2 = *(const float4*)(px + 8);
            float xv[12] = {v0.x, v0.y, v0.z, v0.w, v1.x, v1.y,
                            v1.z, v1.w, v2.x, v2.y, v2.z, v2.w};
            int c = csplit * 64 + chunk * 8 + i;
#pragma unroll
            for (int l = 0; l < LAYERS; ++l) {
                float wv = s_c1[l * Cc + c];
#pragma unroll
                for (int t = 0; t < 12; ++t) acc[l * 12 + t] += xv[t] * wv;
            }
            px += (size_t)Nn * Ll;
        }
    }
    // pair-reduce across chunk parity (lane ^ 32 within wave)
#pragma unroll
    for (int j = 0; j < 48; ++j) acc[j] += __shfl_xor(acc[j], 32, 64);
    int w = tid >> 6;  // wave 0..3
    if ((tid & 32) == 0) {  // even chunk lanes hold the pair sum
#pragma unroll
        for (int j = 0; j < 48; ++j) sred[j * 132 + w * 32 + nl] = acc[j];
    }
    __syncthreads();
    float* G1o = G1 + (size_t)csplit * G1SZ;
    size_t cb = (size_t)ch * LAYERS * Bn * (LH * Nn);
    for (int o = tid; o < 1536; o += 256) {  // 48 j x 32 nl
        int onl = o & 31, j = o >> 5;
        float v = sred[j * 132 + onl] + sred[j * 132 + 32 + onl] +
                  sred[j * 132 + 64 + onl] + sred[j * 132 + 96 + onl];
        int nn = tile * 32 + onl;
        if (nn < Nn) {
            int l = j / 12, t = j % 12;
            int t0 = ch ? (t + 1) : t;  // high channel shifted by left-pad
            G1o[cb + ((size_t)l * Bn + b) * (LH * Nn) + (size_t)t0 * Nn + nn] = v;
        }
    }
    if (tid < 128) {  // zero the unused t-plane (ch0: t0=12, ch1: t0=0)
        int l = tid >> 5, onl = tid & 31;
        int nn = tile * 32 + onl;
        int t0z = ch ? 0 : (LH - 1);
        if (nn < Nn)
            G1o[cb + ((size_t)l * Bn + b) * (LH * Nn) + (size_t)t0z * Nn + nn] = 0.f;
    }
}

// ============================================================================
// G2[ch][l][b][t0][c] = sum_n X[b,c,n,t] * c2[l,n]
// grid (32 ctiles, 32 b, 2 ch), block 256 = 4 waves (one c each), lanes span n.
// 3-stage shfl butterfly + 7 KB sred -> 12 KB LDS -> 8 blocks/CU.
// ============================================================================
__global__ __launch_bounds__(256) void k_g2(const float* __restrict__ XL,
                                            const float* __restrict__ XH,
                                            const float* __restrict__ lc2,
                                            const float* __restrict__ hc2,
                                            float* __restrict__ G2) {
    __shared__ float s_c2[LAYERS * Nn];
    __shared__ float sred[4][48][9];
    int ctile = blockIdx.x;  // 0..31 (4 c each)
    int b = blockIdx.y;
    int ch = blockIdx.z;
    const float* X = ch ? XH : XL;
    const float* c2 = ch ? hc2 : lc2;
    int tid = threadIdx.x;
    for (int j = tid; j < LAYERS * Nn; j += 256) s_c2[j] = c2[j];
    __syncthreads();
    int w = tid >> 6, lane = tid & 63;
    int c = ctile * 4 + w;
    float acc[48];
#pragma unroll
    for (int j = 0; j < 48; ++j) acc[j] = 0.f;
    const float* pb = X + (size_t)(b * Cc + c) * Nn * Ll;
#pragma unroll
    for (int k = 0; k < 5; ++k) {
        int n = k * 64 + lane;
        if (n < Nn) {
            const float* px = pb + (size_t)n * Ll;
            float4 v0 = *(const float4*)(px);
            float4 v1 = *(const float4*)(px + 4);
            float4 v2 = *(const float4*)(px + 8);
            float xv[12] = {v0.x, v0.y, v0.z, v0.w, v1.x, v1.y,
                            v1.z, v1.w, v2.x, v2.y, v2.z, v2.w};
#pragma unroll
            for (int l = 0; l < LAYERS; ++l) {
                float wv = s_c2[l * Nn + n];
#pragma unroll
                for (int t = 0; t < 12; ++t) acc[l * 12 + t] += xv[t] * wv;
            }
        }
    }
    // butterfly over lanes 1,2,4 -> every 8th lane holds 8-lane partial
#pragma unroll
    for (int j = 0; j < 48; ++j) acc[j] += __shfl_xor(acc[j], 1, 64);
#pragma unroll
    for (int j = 0; j < 48; ++j) acc[j] += __shfl_xor(acc[j], 2, 64);
#pragma unroll
    for (int j = 0; j < 48; ++j) acc[j] += __shfl_xor(acc[j], 4, 64);
    if ((lane & 7) == 0) {
        int s = lane >> 3;  // 0..7
#pragma unroll
        for (int j = 0; j < 48; ++j) sred[w][j][s] = acc[j];
    }
    __syncthreads();
    size_t cb = (size_t)ch * LAYERS * Bn * (LH * Cc);
    if (tid < 192) {  // 4 w x 48 j outputs
        int ww = tid / 48, j = tid % 48;
        float v = 0.f;
#pragma unroll
        for (int s = 0; s < 8; ++s) v += sred[ww][j][s];
        int l = j / 12, t = j % 12;
        int t0 = ch ? (t + 1) : t;
        int cc2 = ctile * 4 + ww;
        G2[cb + ((size_t)l * Bn + b) * (LH * Cc) + (size_t)t0 * Cc + cc2] = v;
    } else if (ch && tid < 208) {  // zero plane t0=0 for high channel
        int r = tid - 192;
        int l = r >> 2, ww = r & 3;
        G2[cb + ((size_t)l * Bn + b) * (LH * Cc) + ctile * 4 + ww] = 0.f;
    }
}

// ============================================================================
// GW[ch][l][row=(b*LH+t0)][c] = sum_n (G1p0+G1p1)[ch][l][row][n] * w[ch][l][n][c]
// grid (104 row-tiles of 4, 8 chl); block 256 = 32 c-quads x 8 n-stripes.
// ============================================================================
#define GWR 4
__global__ __launch_bounds__(256) void k_gw(const float* __restrict__ lw,
                                            const float* __restrict__ hw,
                                            const float* __restrict__ G1,
                                            float* __restrict__ GW) {
    __shared__ float sG1[GWR * Nn];
    __shared__ float sred[8][GWR][Cc];  // 16 KB
    int tile = blockIdx.x;  // 0..103
    int chl = blockIdx.y;   // ch*4 + l
    int ch = chl >> 2, l = chl & 3;
    const float* w = (ch ? hw : lw) + (size_t)l * Nn * Cc;
    size_t g1off = (size_t)chl * Bn * (LH * Nn) + (size_t)tile * GWR * Nn;
    const float4* g1a = (const float4*)(G1 + g1off);
    const float4* g1b = (const float4*)(G1 + G1SZ + g1off);
    int tid = threadIdx.x;
    for (int i = tid; i < GWR * Nn / 4; i += 256) {
        float4 pa = g1a[i], pb = g1b[i];
        float4 s = {pa.x + pb.x, pa.y + pb.y, pa.z + pb.z, pa.w + pb.w};
        ((float4*)sG1)[i] = s;
    }
    __syncthreads();
    int c4 = (tid & 31) * 4;  // c base (0,4,...,124)
    int stripe = tid >> 5;    // 0..7
    float4 a0 = {0.f, 0.f, 0.f, 0.f}, a1 = a0, a2 = a0, a3 = a0;
#define GW_FMA(wv, nn)                                         \
    {                                                          \
        float g0 = sG1[0 * Nn + (nn)];                         \
        float g1v = sG1[1 * Nn + (nn)];                        \
        float g2v = sG1[2 * Nn + (nn)];                        \
        float g3v = sG1[3 * Nn + (nn)];                        \
        a0.x += wv.x * g0;  a0.y += wv.y * g0;                 \
        a0.z += wv.z * g0;  a0.w += wv.w * g0;                 \
        a1.x += wv.x * g1v; a1.y += wv.y * g1v;                \
        a1.z += wv.z * g1v; a1.w += wv.w * g1v;                \
        a2.x += wv.x * g2v; a2.y += wv.y * g2v;                \
        a2.z += wv.z * g2v; a2.w += wv.w * g2v;                \
        a3.x += wv.x * g3v; a3.y += wv.y * g3v;                \
        a3.z += wv.z * g3v; a3.w += wv.w * g3v;                \
    }
    int n = stripe;
    for (; n + 24 < Nn; n += 32) {  // 4 strided dwordx4 in flight
        float4 w0 = *(const float4*)(w + (size_t)n * Cc + c4);
        float4 w1 = *(const float4*)(w + (size_t)(n + 8) * Cc + c4);
        float4 w2 = *(const float4*)(w + (size_t)(n + 16) * Cc + c4);
        float4 w3 = *(const float4*)(w + (size_t)(n + 24) * Cc + c4);
        GW_FMA(w0, n);
        GW_FMA(w1, n + 8);
        GW_FMA(w2, n + 16);
        GW_FMA(w3, n + 24);
    }
    for (; n < Nn; n += 8) {
        float4 w0 = *(const float4*)(w + (size_t)n * Cc + c4);
        GW_FMA(w0, n);
    }
#undef GW_FMA
    *(float4*)&sred[stripe][0][c4] = a0;
    *(float4*)&sred[stripe][1][c4] = a1;
    *(float4*)&sred[stripe][2][c4] = a2;
    *(float4*)&sred[stripe][3][c4] = a3;
    __syncthreads();
    float* out = GW + (size_t)chl * Bn * (LH * Cc) + (size_t)tile * GWR * Cc;
    for (int o = tid; o < GWR * Cc; o += 256) {
        int r = o >> 7, cc = o & 127;
        float v = 0.f;
#pragma unroll
        for (int s = 0; s < 8; ++s) v += sred[s][r][cc];
        out[o] = v;
    }
}

// ============================================================================
// M[ch,l,b][t0][t1] = sum_c GW[ch,l,b,t0,c] * G2[ch,l,b,t1,c]
// ============================================================================
__global__ __launch_bounds__(256) void k_m(const float* __restrict__ GW,
                                           const float* __restrict__ G2,
                                           float* __restrict__ M) {
    __shared__ float sGW[LH][SCW];
    __shared__ float sG2[LH][SCW];
    int blk = blockIdx.x;  // (ch*LAYERS + l)*Bn + b
    int ch = blk >> 7;
    int T = ch ? LH : Ll;
    const float* gw = GW + (size_t)blk * (LH * Cc);
    const float* g2 = G2 + (size_t)blk * (LH * Cc);
    int tid = threadIdx.x;
    for (int i = tid; i < LH * Cc; i += 256) {
        int t = i >> 7, c = i & 127;
        sGW[t][c] = gw[i];
        sG2[t][c] = g2[i];
    }
    __syncthreads();
    float* Mo = M + (size_t)blk * (LH * LH);
    for (int i = tid; i < T * T; i += 256) {
        int t0 = i / T, t1 = i % T;
        float a = 0.f;
#pragma unroll 8
        for (int cc = 0; cc < Cc; ++cc) a += sGW[t0][cc] * sG2[t1][cc];
        Mo[t0 * LH + t1] = a;
    }
}

// ============================================================================
// Chain: 5 grid-wide launches (64 blocks = one per (ch,b)); kernel boundaries
// provide the cross-b sync BatchNorm needs. (unchanged, verified)
// ============================================================================
template <int T>
__device__ __forceinline__ void first_impl(int ch, int b,
                                           const float* __restrict__ M,
                                           const float* __restrict__ bb,
                                           const float* __restrict__ v,
                                           float* __restrict__ Lg,
                                           float* __restrict__ Stats) {
    const int TT = T * T;
    __shared__ float sS[LH * LH];
    __shared__ float sA[LH * LH];
    int tid = threadIdx.x;
    const float* Ml = M + ((size_t)(ch * LAYERS + 0) * Bn + b) * (LH * LH);
    if (tid < TT) {
        int t = tid / T, q = tid % T;
        float a = bb[tid] + Ml[t * LH + q];
        sS[tid] = 1.f / (1.f + expf(-a));
    }
    __syncthreads();
    if (tid < TT) {
        int t = tid / T, q = tid % T;
        float a = 0.f;
#pragma unroll
        for (int k = 0; k < T; ++k) a += v[t * T + k] * sS[k * T + q];
        sA[tid] = a;
        Lg[(size_t)(ch * Bn + b) * (LH * LH) + tid] = a;
    }
    __syncthreads();
    if (tid < T) {
        float s = 0.f, ss = 0.f;
#pragma unroll
        for (int t = 0; t < T; ++t) {
            float x = sA[t * T + tid];
            s += x;
            ss += x * x;
        }
        float* St = Stats + (size_t)(0 * 2 + ch) * 2 * (LH * Bn);
        St[tid * Bn + b] = s;
        St[LH * Bn + tid * Bn + b] = ss;
    }
}

__global__ __launch_bounds__(192) void k_first(const float* __restrict__ M,
                                               const float* __restrict__ lb,
                                               const float* __restrict__ lv,
                                               const float* __restrict__ hb,
                                               const float* __restrict__ hv,
                                               float* __restrict__ Lg,
                                               float* __restrict__ Stats) {
    int ch = blockIdx.x >> 5, b = blockIdx.x & 31;
    if (ch == 0)
        first_impl<Ll>(0, b, M, lb, lv, Lg, Stats);
    else
        first_impl<LH>(1, b, M, hb, hv, Lg, Stats);
}

template <int T>
__device__ __forceinline__ void mid_impl(int ch, int b, int l,
                                         const float* __restrict__ M,
                                         const float* __restrict__ bb_all,
                                         const float* __restrict__ v_all,
                                         const float* __restrict__ g_all,
                                         const float* __restrict__ be_all,
                                         float* __restrict__ Lg,
                                         float* __restrict__ Stats,
                                         float* __restrict__ Pws) {
    const int TT = T * T;
    __shared__ float sP[LH * LH], sC[LH * LH], sA[LH * LH], sB[LH * LH], sM[LH * LH];
    __shared__ float sMean[LH], sScale[LH], sShift[LH];
    int tid = threadIdx.x;
    bool first = (l == 0);
    float* Lgb = Lg + (size_t)(ch * Bn + b) * (LH * LH);
    float* Pb = Pws + (size_t)(ch * Bn + b) * (LH * LH);
    if (tid < T) {
        const float* St = Stats + (size_t)(l * 2 + ch) * 2 * (LH * Bn);
        float s = 0.f, ss = 0.f;
        for (int b2 = 0; b2 < Bn; ++b2) {
            s += St[tid * Bn + b2];
            ss += St[LH * Bn + tid * Bn + b2];
        }
        float inv = 1.f / (float)(Bn * T);
        float m = s * inv;
        float var = ss * inv - m * m;
        sMean[tid] = m;
        sScale[tid] = rsqrtf(var + BN_EPS) * g_all[l * T + tid];
        sShift[tid] = be_all[l * T + tid];
    }
    if (tid < TT) {
        sA[tid] = Lgb[tid];
        if (!first) sP[tid] = Pb[tid];
    }
    __syncthreads();
    if (tid < T) {
        float vals[T];
        float mx = -1e30f;
#pragma unroll
        for (int q = 0; q < T; ++q) {
            float x = (sA[tid * T + q] - sMean[q]) * sScale[q] + sShift[q];
            vals[q] = x;
            mx = fmaxf(mx, x);
        }
        float sm = 0.f;
#pragma unroll
        for (int q = 0; q < T; ++q) {
            vals[q] = expf(vals[q] - mx);
            sm += vals[q];
        }
        float inv = 1.f / sm;
#pragma unroll
        for (int q = 0; q < T; ++q) sC[tid * T + q] = vals[q] * inv;
    }
    __syncthreads();
    if (tid < TT) {
        int t0 = tid / T, q = tid % T;
        float a;
        if (first) {
            a = sC[q * T + t0];
        } else {
            a = 0.f;
#pragma unroll
            for (int t = 0; t < T; ++t) a += sP[t0 * T + t] * sC[q * T + t];
        }
        sB[tid] = a;
        Pb[tid] = a;
    }
    const float* Mn = M + ((size_t)(ch * LAYERS + l + 1) * Bn + b) * (LH * LH);
    for (int i = tid; i < T * LH; i += 192) sM[i] = Mn[i];
    __syncthreads();
    if (tid < TT) {
        int t = tid / T, t1 = tid % T;
        float a = 0.f;
#pragma unroll
        for (int t0 = 0; t0 < T; ++t0) a += sB[t0 * T + t] * sM[t0 * LH + t1];
        sA[tid] = a;
    }
    __syncthreads();
    const float* bbn = bb_all + (size_t)(l + 1) * TT;
    if (tid < TT) {
        int t = tid / T, q = tid % T;
        float a = bbn[tid];
#pragma unroll
        for (int t1 = 0; t1 < T; ++t1) a += sA[t * T + t1] * sB[t1 * T + q];
        sP[tid] = 1.f / (1.f + expf(-a));
    }
    __syncthreads();
    const float* vn = v_all + (size_t)(l + 1) * TT;
    if (tid < TT) {
        int t = tid / T, q = tid % T;
        float a = 0.f;
#pragma unroll
        for (int k = 0; k < T; ++k) a += vn[t * T + k] * sP[k * T + q];
        sA[tid] = a;
        Lgb[tid] = a;
    }
    __syncthreads();
    if (tid < T) {
        float s = 0.f, ss = 0.f;
#pragma unroll
        for (int t = 0; t < T; ++t) {
            float x = sA[t * T + tid];
            s += x;
            ss += x * x;
        }
        float* St = Stats + (size_t)((l + 1) * 2 + ch) * 2 * (LH * Bn);
        St[tid * Bn + b] = s;
        St[LH * Bn + tid * Bn + b] = ss;
    }
}

__global__ __launch_bounds__(192) void k_mid(const float* __restrict__ M,
                                             const float* __restrict__ lb,
                                             const float* __restrict__ lv,
                                             const float* __restrict__ lgam,
                                             const float* __restrict__ lbet,
                                             const float* __restrict__ hb,
                                             const float* __restrict__ hv,
                                             const float* __restrict__ hgam,
                                             const float* __restrict__ hbet,
                                             float* __restrict__ Lg,
                                             float* __restrict__ Stats,
                                             float* __restrict__ Pws, int l) {
    int ch = blockIdx.x >> 5, b = blockIdx.x & 31;
    if (ch == 0)
        mid_impl<Ll>(0, b, l, M, lb, lv, lgam, lbet, Lg, Stats, Pws);
    else
        mid_impl<LH>(1, b, l, M, hb, hv, hgam, hbet, Lg, Stats, Pws);
}

template <int T>
__device__ __forceinline__ void last_impl(int ch, int b,
                                          const float* __restrict__ g_all,
                                          const float* __restrict__ be_all,
                                          const float* __restrict__ Lg,
                                          const float* __restrict__ Stats,
                                          const float* __restrict__ Pws,
                                          float* __restrict__ Pcol) {
    const int TT = T * T;
    const int l = LAYERS - 1;
    __shared__ float sP[LH * LH], sC[LH * LH], sA[LH * LH], sB[LH * LH];
    __shared__ float sMean[LH], sScale[LH], sShift[LH];
    int tid = threadIdx.x;
    const float* Lgb = Lg + (size_t)(ch * Bn + b) * (LH * LH);
    const float* Pb = Pws + (size_t)(ch * Bn + b) * (LH * LH);
    if (tid < T) {
        const float* St = Stats + (size_t)(l * 2 + ch) * 2 * (LH * Bn);
        float s = 0.f, ss = 0.f;
        for (int b2 = 0; b2 < Bn; ++b2) {
            s += St[tid * Bn + b2];
            ss += St[LH * Bn + tid * Bn + b2];
        }
        float inv = 1.f / (float)(Bn * T);
        float m = s * inv;
        float var = ss * inv - m * m;
        sMean[tid] = m;
        sScale[tid] = rsqrtf(var + BN_EPS) * g_all[l * T + tid];
        sShift[tid] = be_all[l * T + tid];
    }
    if (tid < TT) {
        sA[tid] = Lgb[tid];
        sP[tid] = Pb[tid];
    }
    __syncthreads();
    if (tid < T) {
        float vals[T];
        float mx = -1e30f;
#pragma unroll
        for (int q = 0; q < T; ++q) {
            float x = (sA[tid * T + q] - sMean[q]) * sScale[q] + sShift[q];
            vals[q] = x;
            mx = fmaxf(mx, x);
        }
        float sm = 0.f;
#pragma unroll
        for (int q = 0; q < T; ++q) {
            vals[q] = expf(vals[q] - mx);
            sm += vals[q];
        }
        float inv = 1.f / sm;
#pragma unroll
        for (int q = 0; q < T; ++q) sC[tid * T + q] = vals[q] * inv;
    }
    __syncthreads();
    if (tid < TT) {
        int t0 = tid / T, q = tid % T;
        float a = 0.f;
#pragma unroll
        for (int t = 0; t < T; ++t) a += sP[t0 * T + t] * sC[q * T + t];
        sB[tid] = a;
    }
    __syncthreads();
    if (tid < T) Pcol[(size_t)ch * Bn * LH + b * LH + tid] = sB[tid * T + (T - 1)];
}

__global__ __launch_bounds__(192) void k_last(const float* __restrict__ lgam,
                                              const float* __restrict__ lbet,
                                              const float* __restrict__ hgam,
                                              const float* __restrict__ hbet,
                                              const float* __restrict__ Lg,
                                              const float* __restrict__ Stats,
                                              const float* __restrict__ Pws,
                                              float* __restrict__ Pcol) {
    int ch = blockIdx.x >> 5, b = blockIdx.x & 31;
    if (ch == 0)
        last_impl<Ll>(0, b, lgam, lbet, Lg, Stats, Pws, Pcol);
    else
        last_impl<LH>(1, b, hgam, hbet, Lg, Stats, Pws, Pcol);
}

// ---- final: residuals + alpha blend using last-column weights (unchanged) ----
__global__ __launch_bounds__(256) void k_final(const float* __restrict__ XL,
                                               const float* __restrict__ XH,
                                               const float* __restrict__ Pcol,
                                               const float* __restrict__ alpha,
                                               float* __restrict__ out) {
    __shared__ float s_pl[Ll];
    __shared__ float s_ph[LH];
    int b = blockIdx.y;
    int tid = threadIdx.x;
    if (tid < Ll) s_pl[tid] = Pcol[b * LH + tid];
    if (tid < LH) s_ph[tid] = Pcol[Bn * LH + b * LH + tid];
    __syncthreads();
    int cn = blockIdx.x * blockDim.x + tid;
    if (cn >= Cc * Nn) return;
    size_t idx = (size_t)b * Cc * Nn + cn;
    const float* pl = XL + idx * Ll;
    const float* ph = XH + idx * Ll;
    float accL = 0.f, accH = 0.f;
#pragma unroll
    for (int t = 0; t < Ll; ++t) {
        accL += pl[t] * s_pl[t];
        accH += ph[t] * s_ph[t + 1];  // high-channel t0=0 plane is the zero pad
    }
    float a = 1.f / (1.f + expf(-alpha[0]));
    float xl = pl[Ll - 1] + accL;
    float xh = ph[Ll - 1] + accH;
    out[idx] = a * xl + (1.f - a) * xh;
}

extern "C" void kernel_launch(void* const* d_in, const int* in_sizes, int n_in,
                              void* d_out, int out_size, void* d_ws, size_t ws_size,
                              hipStream_t stream) {
    const float* XL = (const float*)d_in[0];
    const float* XH = (const float*)d_in[1];
    const float* lc1 = (const float*)d_in[2];
    const float* lc2 = (const float*)d_in[3];
    const float* lw = (const float*)d_in[4];
    const float* lb = (const float*)d_in[5];
    const float* lv = (const float*)d_in[6];
    const float* lg = (const float*)d_in[7];
    const float* lbeta = (const float*)d_in[8];
    const float* hc1 = (const float*)d_in[9];
    const float* hc2 = (const float*)d_in[10];
    const float* hw = (const float*)d_in[11];
    const float* hb = (const float*)d_in[12];
    const float* hv = (const float*)d_in[13];
    const float* hg = (const float*)d_in[14];
    const float* hbeta = (const float*)d_in[15];
    const float* alpha = (const float*)d_in[16];
    float* out = (float*)d_out;

    float* ws = (float*)d_ws;
    float* G1 = ws;                                          // 2 partial buffers
    float* G2 = G1 + 2 * G1SZ;                               // 2*4*32*13*128
    float* M = G2 + (size_t)2 * LAYERS * Bn * LH * Cc;       // 2*4*32*13*13
    float* Pcol = M + (size_t)2 * LAYERS * Bn * LH * LH;     // 2*32*13
    float* Stats = Pcol + (size_t)2 * Bn * LH;               // 16*13*32
    float* Lg = Stats + (size_t)4 * LAYERS * LH * Bn;        // 2*32*169
    float* Pws = Lg + (size_t)2 * Bn * LH * LH;              // 2*32*169
    float* GW = Pws + (size_t)2 * Bn * LH * LH;              // 2*4*32*13*128

    k_g1<<<dim3(20, 32, 2), 256, 0, stream>>>(XL, XH, lc1, hc1, G1);
    k_g2<<<dim3(32, 32, 2), 256, 0, stream>>>(XL, XH, lc2, hc2, G2);
    k_gw<<<dim3(104, 8), 256, 0, stream>>>(lw, hw, G1, GW);
    k_m<<<256, 256, 0, stream>>>(GW, G2, M);
    k_first<<<64, 192, 0, stream>>>(M, lb, lv, hb, hv, Lg, Stats);
    k_mid<<<64, 192, 0, stream>>>(M, lb, lv, lg, lbeta, hb, hv, hg, hbeta, Lg, Stats, Pws, 0);
    k_mid<<<64, 192, 0, stream>>>(M, lb, lv, lg, lbeta, hb, hv, hg, hbeta, Lg, Stats, Pws, 1);
    k_mid<<<64, 192, 0, stream>>>(M, lb, lv, lg, lbeta, hb, hv, hg, hbeta, Lg, Stats, Pws, 2);
    k_last<<<64, 192, 0, stream>>>(lg, lbeta, hg, hbeta, Lg, Stats, Pws, Pcol);
    k_final<<<dim3((Cc * Nn + 255) / 256, Bn), 256, 0, stream>>>(XL, XH, Pcol, alpha, out);
}